// Round 1
// baseline (18.415 us; speedup 1.0000x reference)
//
#include <hip/hip_runtime.h>

#define IMG_H 64
#define IMG_W 64
#define NPIX (IMG_H * IMG_W)

// One block per image. 256 threads, each handles 16 pixels.
__global__ __launch_bounds__(256) void sobel_fused_kernel(
    const float* __restrict__ in,      // (2048,1,64,64)
    const float* __restrict__ weight,  // (1,9)
    const float* __restrict__ wfac_p,  // (1,)
    const float* __restrict__ scale_p, // (1,1)
    float* __restrict__ out)           // (1,2048,1,64,64)
{
    // Padded tile: rows 0..65, cols 0..65 valid; stride 68 floats.
    __shared__ float tile[66][68];
    __shared__ float rmin[4], rmax[4];

    const int img = blockIdx.x;
    const int tid = threadIdx.x;
    const float* __restrict__ src = in + (size_t)img * NPIX;
    float* __restrict__ dst = out + (size_t)img * NPIX;

    // Build the 3x3 kernel: wr = clip(weight,-1,1) * clip(wfac,1,255)
    const float wf = fminf(fmaxf(wfac_p[0], 1.0f), 255.0f);
    float wr[9];
#pragma unroll
    for (int i = 0; i < 9; ++i)
        wr[i] = fminf(fmaxf(weight[i], -1.0f), 1.0f) * wf;

    // Zero the halo border.
    for (int i = tid; i < 66; i += 256) { tile[0][i] = 0.0f; tile[65][i] = 0.0f; }
    for (int i = tid; i < 64; i += 256) { tile[i + 1][0] = 0.0f; tile[i + 1][65] = 0.0f; }

    // Load interior, vectorized float4: 1024 float4 total, 4 per thread.
    const float4* __restrict__ src4 = (const float4*)src;
#pragma unroll
    for (int i = 0; i < 4; ++i) {
        int idx = tid + i * 256;       // float4 index 0..1023
        int row = idx >> 4;            // 16 float4 per row
        int col = (idx & 15) * 4;
        float4 v = src4[idx];
        tile[row + 1][col + 1] = v.x;
        tile[row + 1][col + 2] = v.y;
        tile[row + 1][col + 3] = v.z;
        tile[row + 1][col + 4] = v.w;
    }
    __syncthreads();

    // Each thread: 16 pixels at p = tid + i*256 (coalesced).
    float g[16];
    float gmin = __builtin_inff();
    float gmax = -__builtin_inff();
#pragma unroll
    for (int i = 0; i < 16; ++i) {
        int p = tid + i * 256;
        int r = p >> 6;        // 0..63
        int c = p & 63;        // 0..63
        // window centered at (r,c): tile[r..r+2][c..c+2]
        float a00 = tile[r][c],     a01 = tile[r][c + 1],     a02 = tile[r][c + 2];
        float a10 = tile[r + 1][c], a11 = tile[r + 1][c + 1], a12 = tile[r + 1][c + 2];
        float a20 = tile[r + 2][c], a21 = tile[r + 2][c + 1], a22 = tile[r + 2][c + 2];
        // XLA conv = cross-correlation (no flip).
        float gx = a00 * wr[0] + a01 * wr[1] + a02 * wr[2]
                 + a10 * wr[3] + a11 * wr[4] + a12 * wr[5]
                 + a20 * wr[6] + a21 * wr[7] + a22 * wr[8];
        // transposed kernel: wr.T[ky][kx] = wr[kx*3+ky]
        float gy = a00 * wr[0] + a01 * wr[3] + a02 * wr[6]
                 + a10 * wr[1] + a11 * wr[4] + a12 * wr[7]
                 + a20 * wr[2] + a21 * wr[5] + a22 * wr[8];
        float gi = fabsf(gx) + fabsf(gy);
        g[i] = gi;
        gmin = fminf(gmin, gi);
        gmax = fmaxf(gmax, gi);
    }

    // Wave (64-lane) butterfly reduce.
#pragma unroll
    for (int off = 32; off > 0; off >>= 1) {
        gmin = fminf(gmin, __shfl_xor(gmin, off));
        gmax = fmaxf(gmax, __shfl_xor(gmax, off));
    }
    int wave = tid >> 6;
    if ((tid & 63) == 0) { rmin[wave] = gmin; rmax[wave] = gmax; }
    __syncthreads();
    gmin = fminf(fminf(rmin[0], rmin[1]), fminf(rmin[2], rmin[3]));
    gmax = fmaxf(fmaxf(rmax[0], rmax[1]), fmaxf(rmax[2], rmax[3]));

    const float dx = fmaxf(gmax - gmin, 1.0f);
    const float inv = 255.0f / dx;
    const float invscale = 1.0f / scale_p[0];

#pragma unroll
    for (int i = 0; i < 16; ++i) {
        int p = tid + i * 256;
        dst[p] = floorf((g[i] - gmin) * inv) * invscale;
    }
}

extern "C" void kernel_launch(void* const* d_in, const int* in_sizes, int n_in,
                              void* d_out, int out_size, void* d_ws, size_t ws_size,
                              hipStream_t stream) {
    const float* inp   = (const float*)d_in[0];
    const float* wgt   = (const float*)d_in[1];
    const float* wfac  = (const float*)d_in[2];
    const float* scale = (const float*)d_in[3];
    float* out = (float*)d_out;

    sobel_fused_kernel<<<2048, 256, 0, stream>>>(inp, wgt, wfac, scale, out);
}